// Round 6
// baseline (231.600 us; speedup 1.0000x reference)
//
#include <hip/hip_runtime.h>
#include <math.h>

// Problem constants: B=1, C=64, D=H=W=16, HEADS=4, HD=16
#define CN   262144        // C * 4096 floats per [C, D, H, W] tensor

typedef __attribute__((ext_vector_type(8))) short short8;   // 8 bf16 (4 VGPRs)
typedef __attribute__((ext_vector_type(4))) float float4v;  // MFMA C/D

static __device__ __forceinline__ unsigned short f2bf(float f) {
    union { float f; unsigned u; } v; v.f = f;
    unsigned r = (v.u + 0x7FFFu + ((v.u >> 16) & 1u)) >> 16;   // RNE
    return (unsigned short)r;
}

// ---------------------------------------------------------------------------
// Stage 1: spatial conv 3x3 over (H,W), per depth slice. pad (0,1,1).
// 256 blocks -> 1 wave/SIMD: VGPRs are free, so (256,1) + unroll 4 for ILP.
__global__ __launch_bounds__(256, 1) void conv_sp_kernel(
        const float* __restrict__ x, const float* __restrict__ w,
        const float* __restrict__ b, float* __restrict__ y) {
    __shared__ float ws[2304];          // 4 co x 576
    int cog = blockIdx.x >> 4;          // 0..15
    int d   = blockIdx.x & 15;
    int tid = threadIdx.x;
    for (int idx = tid; idx < 2304; idx += 256) ws[idx] = w[cog * 4 * 576 + idx];
    __syncthreads();
    int wv = tid >> 6;                  // wave -> co within group
    int co = cog * 4 + wv;
    int t  = tid & 63;
    int h  = t >> 2;
    int wq = t & 3;                     // w base = wq*4
    float bias = b[co];
    float ax = bias, ay = bias, az = bias, aw = bias;
    const float* wsc = ws + wv * 576;
    #pragma unroll 4
    for (int ci = 0; ci < 64; ++ci) {
        const float* row = x + ci * 4096 + d * 256;
        const float* wc  = wsc + ci * 9;
        #pragma unroll
        for (int dh = 0; dh < 3; ++dh) {
            int hh = h + dh - 1;
            if (hh < 0 || hh > 15) continue;
            const float* r = row + hh * 16 + wq * 4;
            float4 q0 = *(const float4*)r;
            float lm = (wq > 0) ? r[-1] : 0.f;
            float rp = (wq < 3) ? r[4]  : 0.f;
            float wL = wc[dh * 3 + 0], wM = wc[dh * 3 + 1], wR = wc[dh * 3 + 2];
            ax += wL * lm   + wM * q0.x + wR * q0.y;
            ay += wL * q0.x + wM * q0.y + wR * q0.z;
            az += wL * q0.y + wM * q0.z + wR * q0.w;
            aw += wL * q0.z + wM * q0.w + wR * rp;
        }
    }
    float4 out = {ax, ay, az, aw};
    *(float4*)(y + co * 4096 + d * 256 + t * 4) = out;
}

// ---------------------------------------------------------------------------
// Stage 2: spectral conv, 3 taps over D. pad (1,0,0). float4 over positions.
// 256 blocks -> 1 wave/SIMD: (256,1) + unroll 8 (24 float4 loads in flight).
__global__ __launch_bounds__(256, 1) void conv_spec_kernel(
        const float* __restrict__ y1, const float* __restrict__ w,
        const float* __restrict__ b, float* __restrict__ y2) {
    __shared__ float ws[192];
    int co = blockIdx.x >> 2;
    int pb = blockIdx.x & 3;
    int tid = threadIdx.x;
    if (tid < 192) ws[tid] = w[co * 192 + tid];
    __syncthreads();
    int p0 = (pb * 256 + tid) * 4;      // float index, 4 consecutive positions
    int d  = p0 >> 8;                   // wave-uniform (64 tids span one d)
    float bias = b[co];
    float ax = bias, ay = bias, az = bias, aw = bias;
    #pragma unroll 8
    for (int ci = 0; ci < 64; ++ci) {
        const float* base = y1 + ci * 4096 + p0;
        float w0 = ws[ci * 3], w1 = ws[ci * 3 + 1], w2 = ws[ci * 3 + 2];
        if (d > 0) {
            float4 a = *(const float4*)(base - 256);
            ax += w0 * a.x; ay += w0 * a.y; az += w0 * a.z; aw += w0 * a.w;
        }
        float4 m = *(const float4*)base;
        ax += w1 * m.x; ay += w1 * m.y; az += w1 * m.z; aw += w1 * m.w;
        if (d < 15) {
            float4 c = *(const float4*)(base + 256);
            ax += w2 * c.x; ay += w2 * c.y; az += w2 * c.z; aw += w2 * c.w;
        }
    }
    float4 out = {ax, ay, az, aw};
    *(float4*)(y2 + co * 4096 + p0) = out;
}

// ---------------------------------------------------------------------------
// Stage 3: 1x1x1 QKV conv -> bf16 MFMA-ready layouts.
// 768 blocks = 3 blocks/CU: keep default bounds; unroll 8 for ILP.
__global__ __launch_bounds__(256) void qkv_kernel(
        const float* __restrict__ y2, const float* __restrict__ w,
        const float* __restrict__ b,
        unsigned short* __restrict__ qb, unsigned short* __restrict__ kb,
        unsigned short* __restrict__ vtb) {
    __shared__ float ws[64];
    int oc = blockIdx.x >> 2;           // 0..191
    int pb = blockIdx.x & 3;
    int tid = threadIdx.x;
    if (tid < 64) ws[tid] = w[oc * 64 + tid];
    __syncthreads();
    int p0 = (pb * 256 + tid) * 4;
    float bias = b[oc];
    float ax = bias, ay = bias, az = bias, aw = bias;
    #pragma unroll 8
    for (int ci = 0; ci < 64; ++ci) {
        float4 a = *(const float4*)(y2 + ci * 4096 + p0);
        float wc = ws[ci];
        ax += wc * a.x; ay += wc * a.y; az += wc * a.z; aw += wc * a.w;
    }
    int which = oc >> 6;                // 0=q 1=k 2=v
    int hd = oc & 63;
    int head = hd >> 4, dim = hd & 15;
    if (which == 0) { ax *= 0.25f; ay *= 0.25f; az *= 0.25f; aw *= 0.25f; }
    if (which == 2) {
        int m = p0 >> 8, h = (p0 >> 4) & 15, w0 = p0 & 15;
        int kap = 8 * (w0 >> 2) + 4 * (h & 1);          // w0 % 4 == 0
        unsigned short* dst = vtb + ((head * 16 + m) * 8 + (h >> 1)) * 512
                                  + dim * 32 + kap;
        unsigned r0 = (unsigned)f2bf(ax) | ((unsigned)f2bf(ay) << 16);
        unsigned r1 = (unsigned)f2bf(az) | ((unsigned)f2bf(aw) << 16);
        *(unsigned*)(dst)     = r0;
        *(unsigned*)(dst + 2) = r1;
    } else {
        unsigned short* dst = (which == 0 ? qb : kb) + head * 65536 + p0 * 16 + dim;
        dst[0]  = f2bf(ax); dst[16] = f2bf(ay);
        dst[32] = f2bf(az); dst[48] = f2bf(aw);
    }
}

// ---------------------------------------------------------------------------
// Stage 4: retention attention via MFMA (unchanged from round 5 — verified).
__global__ __launch_bounds__(512, 2) void attn_kernel(
        const unsigned short* __restrict__ qb, const unsigned short* __restrict__ kb,
        const unsigned short* __restrict__ vtb, const float* __restrict__ gamma,
        float* __restrict__ ao0, float* __restrict__ ao1,
        float* __restrict__ ao2, float* __restrict__ ao3) {
    __shared__ __align__(16) unsigned short ksh[4096];   // [n][o][d16] bf16, 8 KB
    __shared__ __align__(16) unsigned short vsh[4096];   // [np][dim][kappa32], 8 KB
    __shared__ float gp[32];
    int tid = threadIdx.x;
    int bI = blockIdx.x;
    int head = bI >> 7;                 // 4
    int mg   = (bI >> 5) & 3;           // 4 m-quarters
    int oct  = bI & 31;                 // 32 q-octets per head

    if (tid < 32) {
        float g = 1.f / (1.f + __expf(-gamma[0]));
        gp[tid] = __powf(g, (float)tid);
    }

    int wv = tid >> 6, lane = tid & 63;
    int quad = lane >> 4, l15 = lane & 15;
    int t = oct * 8 + wv;               // tile index 0..255 (= i*16 + j)
    int i = t >> 4, j = t & 15;

    short8 zero8 = {0, 0, 0, 0, 0, 0, 0, 0};
    float4v czero = {0.f, 0.f, 0.f, 0.f};

    // Q fragment (B operand): B[k=d][n=q]; zero for d>=16 (quads 2,3)
    short8 qf = zero8;
    if (quad < 2)
        qf = *(const short8*)(qb + head * 65536 + (t * 16 + l15) * 16 + quad * 8);

    __syncthreads();                    // gp ready
    float wd[4];
    #pragma unroll
    for (int r = 0; r < 4; ++r) wd[r] = gp[abs(l15 - (quad * 4 + r))];

    float4v O = czero;

    for (int mm = 0; mm < 4; ++mm) {
        int m = mg * 4 + mm;
        __syncthreads();                // previous slab fully consumed
        ((float4*)ksh)[tid] = ((const float4*)(kb  + head * 65536 + m * 4096))[tid];
        ((float4*)vsh)[tid] = ((const float4*)(vtb + (head * 16 + m) * 4096))[tid];
        __syncthreads();

        int eim = abs(i - m);
        #pragma unroll
        for (int np = 0; np < 8; ++np) {
            short8 a2 = zero8;
            #pragma unroll
            for (int s = 0; s < 2; ++s) {
                int n = np * 2 + s;
                short8 a1 = zero8;
                if (quad < 2)
                    a1 = *(const short8*)(ksh + n * 256 + l15 * 16 + quad * 8);
                float4v d1 = __builtin_amdgcn_mfma_f32_16x16x32_bf16(a1, qf, czero, 0, 0, 0);
                float smn = gp[eim + abs(j - n)];        // wave-uniform broadcast
                float e0 = __expf(d1[0] * smn * wd[0]);
                float e1 = __expf(d1[1] * smn * wd[1]);
                float e2 = __expf(d1[2] * smn * wd[2]);
                float e3 = __expf(d1[3] * smn * wd[3]);
                float sm = e0 + e1 + e2 + e3;
                sm += __shfl_xor(sm, 16);
                sm += __shfl_xor(sm, 32);
                float inv = __builtin_amdgcn_rcpf(sm);
                a2[s * 4 + 0] = (short)f2bf(e0 * inv);
                a2[s * 4 + 1] = (short)f2bf(e1 * inv);
                a2[s * 4 + 2] = (short)f2bf(e2 * inv);
                a2[s * 4 + 3] = (short)f2bf(e3 * inv);
            }
            short8 b2 = *(const short8*)(vsh + np * 512 + l15 * 32 + quad * 8);
            O = __builtin_amdgcn_mfma_f32_16x16x32_bf16(a2, b2, O, 0, 0, 0);
        }
    }

    // O: col=lane&15=dim, row=quad*4+reg=query-w. 4 consecutive positions.
    float* aop = (mg == 0) ? ao0 : ((mg == 1) ? ao1 : ((mg == 2) ? ao2 : ao3));
    float4 ov = {O[0], O[1], O[2], O[3]};
    *(float4*)(aop + (head * 16 + l15) * 4096 + t * 16 + quad * 4) = ov;
}

// ---------------------------------------------------------------------------
// Stage 5: 1x1x1 projection conv; sums the four m-quarter partials.
// 256 blocks -> 1 wave/SIMD: (256,1) + unroll 4 (16 float4 loads in flight).
__global__ __launch_bounds__(256, 1) void proj_kernel(
        const float* __restrict__ ao0, const float* __restrict__ ao1,
        const float* __restrict__ ao2, const float* __restrict__ ao3,
        const float* __restrict__ w, const float* __restrict__ b,
        float* __restrict__ out) {
    __shared__ float ws[64];
    int oc = blockIdx.x >> 2;
    int pb = blockIdx.x & 3;
    int tid = threadIdx.x;
    if (tid < 64) ws[tid] = w[oc * 64 + tid];
    __syncthreads();
    int p0 = (pb * 256 + tid) * 4;
    float bias = b[oc];
    float ax = bias, ay = bias, az = bias, aw = bias;
    #pragma unroll 4
    for (int ci = 0; ci < 64; ++ci) {
        float4 a = *(const float4*)(ao0 + ci * 4096 + p0);
        float c = ws[ci];
        float4 d = *(const float4*)(ao1 + ci * 4096 + p0);
        float4 e = *(const float4*)(ao2 + ci * 4096 + p0);
        float4 f = *(const float4*)(ao3 + ci * 4096 + p0);
        ax += c * (a.x + d.x + e.x + f.x);
        ay += c * (a.y + d.y + e.y + f.y);
        az += c * (a.z + d.z + e.z + f.z);
        aw += c * (a.w + d.w + e.w + f.w);
    }
    float4 o4 = {ax, ay, az, aw};
    *(float4*)(out + oc * 4096 + p0) = o4;
}

// ---------------------------------------------------------------------------
extern "C" void kernel_launch(void* const* d_in, const int* in_sizes, int n_in,
                              void* d_out, int out_size, void* d_ws, size_t ws_size,
                              hipStream_t stream) {
    const float* x      = (const float*)d_in[0];
    const float* gamma  = (const float*)d_in[1];
    const float* w_sp   = (const float*)d_in[2];
    const float* b_sp   = (const float*)d_in[3];
    const float* w_spec = (const float*)d_in[4];
    const float* b_spec = (const float*)d_in[5];
    const float* w_qkv  = (const float*)d_in[6];
    const float* b_qkv  = (const float*)d_in[7];
    const float* w_proj = (const float*)d_in[8];
    const float* b_proj = (const float*)d_in[9];
    float* out = (float*)d_out;

    float* ws = (float*)d_ws;
    float* y1  = ws;                         // [64][4096] f32; reused as ao0
    float* y2  = ws + CN;                    // [64][4096] f32; reused as ao1
    unsigned short* qb  = (unsigned short*)(ws + 2 * CN);            // 512 KB bf16
    unsigned short* kb  = (unsigned short*)(ws + 2 * CN + CN / 2);   // 512 KB bf16
    unsigned short* vtb = (unsigned short*)(ws + 3 * CN);            // 512 KB bf16
    float* ao2 = ws + 3 * CN + CN / 2;       // [64][4096] partial (m 8..11)
    float* ao3 = ws + 4 * CN + CN / 2;       // [64][4096] partial (m 12..15)
    float* ao0 = y1;                         // safe: y1 consumed by conv_spec
    float* ao1 = y2;                         // safe: y2 consumed by qkv

    conv_sp_kernel  <<<256, 256, 0, stream>>>(x, w_sp, b_sp, y1);
    conv_spec_kernel<<<256, 256, 0, stream>>>(y1, w_spec, b_spec, y2);
    qkv_kernel      <<<768, 256, 0, stream>>>(y2, w_qkv, b_qkv, qb, kb, vtb);
    attn_kernel     <<<512, 512, 0, stream>>>(qb, kb, vtb, gamma, ao0, ao1, ao2, ao3);
    proj_kernel     <<<256, 256, 0, stream>>>(ao0, ao1, ao2, ao3, w_proj, b_proj, out);
}

// Round 7
// 157.563 us; speedup vs baseline: 1.4699x; 1.4699x over previous
//
#include <hip/hip_runtime.h>
#include <math.h>

// Problem constants: B=1, C=64, D=H=W=16, HEADS=4, HD=16
#define CN   262144        // C * 4096 floats per [C, D, H, W] tensor

typedef __attribute__((ext_vector_type(8))) short short8;   // 8 bf16 (4 VGPRs)
typedef __attribute__((ext_vector_type(4))) float float4v;  // MFMA C/D

static __device__ __forceinline__ unsigned short f2bf(float f) {
    union { float f; unsigned u; } v; v.f = f;
    unsigned r = (v.u + 0x7FFFu + ((v.u >> 16) & 1u)) >> 16;   // RNE
    return (unsigned short)r;
}

// ---------------------------------------------------------------------------
// Stage 1: spatial conv 3x3 over (H,W). pad (0,1,1).
// Block = (co, d): 1024 blocks. 4 waves split ci (16 each), LDS reduce.
// Chain is 16 dependent load-batches (was 64) and 4 blocks/CU (was 1 wave/SIMD).
__global__ __launch_bounds__(256) void conv_sp_kernel(
        const float* __restrict__ x, const float* __restrict__ w,
        const float* __restrict__ b, float* __restrict__ y) {
    __shared__ float ws[576];
    __shared__ float red[4][256];
    int co = blockIdx.x >> 4;
    int d  = blockIdx.x & 15;
    int tid = threadIdx.x;
    for (int idx = tid; idx < 576; idx += 256) ws[idx] = w[co * 576 + idx];
    __syncthreads();
    int og  = tid & 63;                 // output quad: h = og>>2, w-base = (og&3)*4
    int grp = tid >> 6;                 // ci group
    int h = og >> 2, wq = og & 3;
    float ax = 0.f, ay = 0.f, az = 0.f, aw = 0.f;
    #pragma unroll 4
    for (int c2 = 0; c2 < 16; ++c2) {
        int ci = grp * 16 + c2;
        const float* row = x + ci * 4096 + d * 256;
        const float* wc  = ws + ci * 9;
        #pragma unroll
        for (int dh = 0; dh < 3; ++dh) {
            int hh = h + dh - 1;
            if (hh < 0 || hh > 15) continue;
            const float* r = row + hh * 16 + wq * 4;
            float4 q0 = *(const float4*)r;
            float lm = (wq > 0) ? r[-1] : 0.f;
            float rp = (wq < 3) ? r[4]  : 0.f;
            float wL = wc[dh * 3 + 0], wM = wc[dh * 3 + 1], wR = wc[dh * 3 + 2];
            ax += wL * lm   + wM * q0.x + wR * q0.y;
            ay += wL * q0.x + wM * q0.y + wR * q0.z;
            az += wL * q0.y + wM * q0.z + wR * q0.w;
            aw += wL * q0.z + wM * q0.w + wR * rp;
        }
    }
    float4 part = {ax, ay, az, aw};
    *(float4*)&red[grp][og * 4] = part;
    __syncthreads();
    float s = red[0][tid] + red[1][tid] + red[2][tid] + red[3][tid] + b[co];
    y[co * 4096 + d * 256 + tid] = s;
}

// ---------------------------------------------------------------------------
// Stage 2: spectral conv, 3 taps over D. pad (1,0,0).
// Block = (co, d): 1024 blocks, 4-way ci split + LDS reduce.
__global__ __launch_bounds__(256) void conv_spec_kernel(
        const float* __restrict__ y1, const float* __restrict__ w,
        const float* __restrict__ b, float* __restrict__ y2) {
    __shared__ float ws[192];
    __shared__ float red[4][256];
    int co = blockIdx.x >> 4;
    int d  = blockIdx.x & 15;
    int tid = threadIdx.x;
    if (tid < 192) ws[tid] = w[co * 192 + tid];
    __syncthreads();
    int og  = tid & 63;
    int grp = tid >> 6;
    int p0 = d * 256 + og * 4;
    float ax = 0.f, ay = 0.f, az = 0.f, aw = 0.f;
    #pragma unroll 4
    for (int c2 = 0; c2 < 16; ++c2) {
        int ci = grp * 16 + c2;
        const float* base = y1 + ci * 4096 + p0;
        float w0 = ws[ci * 3], w1 = ws[ci * 3 + 1], w2 = ws[ci * 3 + 2];
        if (d > 0) {
            float4 a = *(const float4*)(base - 256);
            ax += w0 * a.x; ay += w0 * a.y; az += w0 * a.z; aw += w0 * a.w;
        }
        float4 m = *(const float4*)base;
        ax += w1 * m.x; ay += w1 * m.y; az += w1 * m.z; aw += w1 * m.w;
        if (d < 15) {
            float4 c = *(const float4*)(base + 256);
            ax += w2 * c.x; ay += w2 * c.y; az += w2 * c.z; aw += w2 * c.w;
        }
    }
    float4 part = {ax, ay, az, aw};
    *(float4*)&red[grp][og * 4] = part;
    __syncthreads();
    float s = red[0][tid] + red[1][tid] + red[2][tid] + red[3][tid] + b[co];
    y2[co * 4096 + d * 256 + tid] = s;
}

// ---------------------------------------------------------------------------
// Stage 3: 1x1x1 QKV conv -> bf16 MFMA-ready layouts.
// Block = (oc, d): 3072 blocks, 4-way ci split + LDS reduce.
//   qb/kb: [head][pos][d16] bf16 (q pre-scaled by 0.25)
//   vtb:   [head][m][npair=h>>1][dim][kappa32], kappa = 8*(w>>2)+4*(h&1)+(w&3)
__global__ __launch_bounds__(256) void qkv_kernel(
        const float* __restrict__ y2, const float* __restrict__ w,
        const float* __restrict__ b,
        unsigned short* __restrict__ qb, unsigned short* __restrict__ kb,
        unsigned short* __restrict__ vtb) {
    __shared__ float ws[64];
    __shared__ float red[4][256];
    int oc = blockIdx.x >> 4;           // 0..191
    int d  = blockIdx.x & 15;
    int tid = threadIdx.x;
    if (tid < 64) ws[tid] = w[oc * 64 + tid];
    __syncthreads();
    int og  = tid & 63;
    int grp = tid >> 6;
    int p0 = d * 256 + og * 4;
    float ax = 0.f, ay = 0.f, az = 0.f, aw = 0.f;
    #pragma unroll 4
    for (int c2 = 0; c2 < 16; ++c2) {
        int ci = grp * 16 + c2;
        float4 a = *(const float4*)(y2 + ci * 4096 + p0);
        float wc = ws[ci];
        ax += wc * a.x; ay += wc * a.y; az += wc * a.z; aw += wc * a.w;
    }
    float4 part = {ax, ay, az, aw};
    *(float4*)&red[grp][og * 4] = part;
    __syncthreads();
    float val = red[0][tid] + red[1][tid] + red[2][tid] + red[3][tid] + b[oc];
    int which = oc >> 6;                // 0=q 1=k 2=v
    int hd = oc & 63;
    int head = hd >> 4, dim = hd & 15;
    if (which == 0) val *= 0.25f;
    int p = d * 256 + tid;              // global position
    if (which == 2) {
        int h = (p >> 4) & 15, w0 = p & 15;
        int kap = 8 * (w0 >> 2) + 4 * (h & 1) + (w0 & 3);
        vtb[((head * 16 + d) * 8 + (h >> 1)) * 512 + dim * 32 + kap] = f2bf(val);
    } else {
        (which == 0 ? qb : kb)[head * 65536 + p * 16 + dim] = f2bf(val);
    }
}

// ---------------------------------------------------------------------------
// Stage 4: retention attention via MFMA (unchanged — verified).
__global__ __launch_bounds__(512, 2) void attn_kernel(
        const unsigned short* __restrict__ qb, const unsigned short* __restrict__ kb,
        const unsigned short* __restrict__ vtb, const float* __restrict__ gamma,
        float* __restrict__ ao0, float* __restrict__ ao1,
        float* __restrict__ ao2, float* __restrict__ ao3) {
    __shared__ __align__(16) unsigned short ksh[4096];   // [n][o][d16] bf16, 8 KB
    __shared__ __align__(16) unsigned short vsh[4096];   // [np][dim][kappa32], 8 KB
    __shared__ float gp[32];
    int tid = threadIdx.x;
    int bI = blockIdx.x;
    int head = bI >> 7;                 // 4
    int mg   = (bI >> 5) & 3;           // 4 m-quarters
    int oct  = bI & 31;                 // 32 q-octets per head

    if (tid < 32) {
        float g = 1.f / (1.f + __expf(-gamma[0]));
        gp[tid] = __powf(g, (float)tid);
    }

    int wv = tid >> 6, lane = tid & 63;
    int quad = lane >> 4, l15 = lane & 15;
    int t = oct * 8 + wv;               // tile index 0..255 (= i*16 + j)
    int i = t >> 4, j = t & 15;

    short8 zero8 = {0, 0, 0, 0, 0, 0, 0, 0};
    float4v czero = {0.f, 0.f, 0.f, 0.f};

    // Q fragment (B operand): B[k=d][n=q]; zero for d>=16 (quads 2,3)
    short8 qf = zero8;
    if (quad < 2)
        qf = *(const short8*)(qb + head * 65536 + (t * 16 + l15) * 16 + quad * 8);

    __syncthreads();                    // gp ready
    float wd[4];
    #pragma unroll
    for (int r = 0; r < 4; ++r) wd[r] = gp[abs(l15 - (quad * 4 + r))];

    float4v O = czero;

    for (int mm = 0; mm < 4; ++mm) {
        int m = mg * 4 + mm;
        __syncthreads();                // previous slab fully consumed
        ((float4*)ksh)[tid] = ((const float4*)(kb  + head * 65536 + m * 4096))[tid];
        ((float4*)vsh)[tid] = ((const float4*)(vtb + (head * 16 + m) * 4096))[tid];
        __syncthreads();

        int eim = abs(i - m);
        #pragma unroll
        for (int np = 0; np < 8; ++np) {
            short8 a2 = zero8;
            #pragma unroll
            for (int s = 0; s < 2; ++s) {
                int n = np * 2 + s;
                short8 a1 = zero8;
                if (quad < 2)
                    a1 = *(const short8*)(ksh + n * 256 + l15 * 16 + quad * 8);
                float4v d1 = __builtin_amdgcn_mfma_f32_16x16x32_bf16(a1, qf, czero, 0, 0, 0);
                float smn = gp[eim + abs(j - n)];        // wave-uniform broadcast
                float e0 = __expf(d1[0] * smn * wd[0]);
                float e1 = __expf(d1[1] * smn * wd[1]);
                float e2 = __expf(d1[2] * smn * wd[2]);
                float e3 = __expf(d1[3] * smn * wd[3]);
                float sm = e0 + e1 + e2 + e3;
                sm += __shfl_xor(sm, 16);
                sm += __shfl_xor(sm, 32);
                float inv = __builtin_amdgcn_rcpf(sm);
                a2[s * 4 + 0] = (short)f2bf(e0 * inv);
                a2[s * 4 + 1] = (short)f2bf(e1 * inv);
                a2[s * 4 + 2] = (short)f2bf(e2 * inv);
                a2[s * 4 + 3] = (short)f2bf(e3 * inv);
            }
            short8 b2 = *(const short8*)(vsh + np * 512 + l15 * 32 + quad * 8);
            O = __builtin_amdgcn_mfma_f32_16x16x32_bf16(a2, b2, O, 0, 0, 0);
        }
    }

    // O: col=lane&15=dim, row=quad*4+reg=query-w. 4 consecutive positions.
    float* aop = (mg == 0) ? ao0 : ((mg == 1) ? ao1 : ((mg == 2) ? ao2 : ao3));
    float4 ov = {O[0], O[1], O[2], O[3]};
    *(float4*)(aop + (head * 16 + l15) * 4096 + t * 16 + quad * 4) = ov;
}

// ---------------------------------------------------------------------------
// Stage 5: 1x1x1 projection; sums four m-quarter partials.
// Block = (oc, d): 1024 blocks, 4-way ci split + LDS reduce.
__global__ __launch_bounds__(256) void proj_kernel(
        const float* __restrict__ ao0, const float* __restrict__ ao1,
        const float* __restrict__ ao2, const float* __restrict__ ao3,
        const float* __restrict__ w, const float* __restrict__ b,
        float* __restrict__ out) {
    __shared__ float ws[64];
    __shared__ float red[4][256];
    int oc = blockIdx.x >> 4;
    int d  = blockIdx.x & 15;
    int tid = threadIdx.x;
    if (tid < 64) ws[tid] = w[oc * 64 + tid];
    __syncthreads();
    int og  = tid & 63;
    int grp = tid >> 6;
    int p0 = d * 256 + og * 4;
    float ax = 0.f, ay = 0.f, az = 0.f, aw = 0.f;
    #pragma unroll 4
    for (int c2 = 0; c2 < 16; ++c2) {
        int ci = grp * 16 + c2;
        float  c = ws[ci];
        float4 a = *(const float4*)(ao0 + ci * 4096 + p0);
        float4 e = *(const float4*)(ao1 + ci * 4096 + p0);
        float4 f = *(const float4*)(ao2 + ci * 4096 + p0);
        float4 g = *(const float4*)(ao3 + ci * 4096 + p0);
        ax += c * (a.x + e.x + f.x + g.x);
        ay += c * (a.y + e.y + f.y + g.y);
        az += c * (a.z + e.z + f.z + g.z);
        aw += c * (a.w + e.w + f.w + g.w);
    }
    float4 part = {ax, ay, az, aw};
    *(float4*)&red[grp][og * 4] = part;
    __syncthreads();
    float s = red[0][tid] + red[1][tid] + red[2][tid] + red[3][tid] + b[oc];
    out[oc * 4096 + d * 256 + tid] = s;
}

// ---------------------------------------------------------------------------
extern "C" void kernel_launch(void* const* d_in, const int* in_sizes, int n_in,
                              void* d_out, int out_size, void* d_ws, size_t ws_size,
                              hipStream_t stream) {
    const float* x      = (const float*)d_in[0];
    const float* gamma  = (const float*)d_in[1];
    const float* w_sp   = (const float*)d_in[2];
    const float* b_sp   = (const float*)d_in[3];
    const float* w_spec = (const float*)d_in[4];
    const float* b_spec = (const float*)d_in[5];
    const float* w_qkv  = (const float*)d_in[6];
    const float* b_qkv  = (const float*)d_in[7];
    const float* w_proj = (const float*)d_in[8];
    const float* b_proj = (const float*)d_in[9];
    float* out = (float*)d_out;

    float* ws = (float*)d_ws;
    float* y1  = ws;                         // [64][4096] f32; reused as ao0
    float* y2  = ws + CN;                    // [64][4096] f32; reused as ao1
    unsigned short* qb  = (unsigned short*)(ws + 2 * CN);            // 512 KB bf16
    unsigned short* kb  = (unsigned short*)(ws + 2 * CN + CN / 2);   // 512 KB bf16
    unsigned short* vtb = (unsigned short*)(ws + 3 * CN);            // 512 KB bf16
    float* ao2 = ws + 3 * CN + CN / 2;       // [64][4096] partial (m 8..11)
    float* ao3 = ws + 4 * CN + CN / 2;       // [64][4096] partial (m 12..15)
    float* ao0 = y1;                         // safe: y1 consumed by conv_spec
    float* ao1 = y2;                         // safe: y2 consumed by qkv

    conv_sp_kernel  <<<1024, 256, 0, stream>>>(x, w_sp, b_sp, y1);
    conv_spec_kernel<<<1024, 256, 0, stream>>>(y1, w_spec, b_spec, y2);
    qkv_kernel      <<<3072, 256, 0, stream>>>(y2, w_qkv, b_qkv, qb, kb, vtb);
    attn_kernel     <<<512, 512, 0, stream>>>(qb, kb, vtb, gamma, ao0, ao1, ao2, ao3);
    proj_kernel     <<<1024, 256, 0, stream>>>(ao0, ao1, ao2, ao3, w_proj, b_proj, out);
}